// Round 1
// baseline (4314.024 us; speedup 1.0000x reference)
//
#include <hip/hip_runtime.h>
#include <hip/hip_bf16.h>

#define BATCH 1024
#define HID   512
#define OUTW  348   // 12 * (8+6+4+11)

using short8 = __attribute__((ext_vector_type(8))) short;
using bf16x8 = __attribute__((ext_vector_type(8))) __bf16;
using f32x4  = __attribute__((ext_vector_type(4))) float;

__device__ __forceinline__ float bf2f(unsigned short u) {
  union { unsigned int i; float f; } x; x.i = ((unsigned int)u) << 16; return x.f;
}
__device__ __forceinline__ unsigned short f2bf(float f) {
  __hip_bfloat16 b = __float2bfloat16(f);
  return __builtin_bit_cast(unsigned short, b);
}
__device__ __forceinline__ float sigm(float x) { return 1.0f / (1.0f + __expf(-x)); }

__device__ __forceinline__ f32x4 mfma_bf16(short8 a, short8 b, f32x4 c) {
  return __builtin_amdgcn_mfma_f32_16x16x32_bf16(
      __builtin_bit_cast(bf16x8, a), __builtin_bit_cast(bf16x8, b), c, 0, 0, 0);
}

// ---------------- setup kernels ----------------

__global__ void k_convert(const float* __restrict__ src, unsigned short* __restrict__ dst, int n) {
  int i = (blockIdx.x * blockDim.x + threadIdx.x) * 4;
  if (i + 3 < n) {
    float4 v = *(const float4*)(src + i);
    dst[i + 0] = f2bf(v.x); dst[i + 1] = f2bf(v.y);
    dst[i + 2] = f2bf(v.z); dst[i + 3] = f2bf(v.w);
  } else {
    for (int j = 0; j < 4 && i + j < n; ++j) dst[i + j] = f2bf(src[i + j]);
  }
}

__global__ void k_bias(const float* __restrict__ bih, const float* __restrict__ bhh,
                       float* __restrict__ bsum) {
  int i = blockIdx.x * blockDim.x + threadIdx.x;
  if (i < 4096) bsum[i] = bih[i] + bhh[i];
}

__global__ void k_zero(uint4* __restrict__ p, int n16) {
  int i = blockIdx.x * blockDim.x + threadIdx.x;
  if (i < n16) p[i] = make_uint4(0u, 0u, 0u, 0u);
}

// P[0][r][a] = bprev[a]
__global__ void k_p0(float* __restrict__ P, const float* __restrict__ bprev) {
  int i = blockIdx.x * blockDim.x + threadIdx.x;  // < 1024*64
  P[i] = bprev[i & 63];
}

// ---------------- LSTM gates + cell update ----------------
// One layer-step: G = Xin @ Wih^T + Hprev @ Whh^T + bias; cell update; writes C, Hout(bf16).
// Grid (32,16), block 256 (4 waves). Wave tile: 16 rows x 16 cells x 4 gates.
__device__ __forceinline__ void gemm_half(const unsigned short* __restrict__ A,
                                          const unsigned short* __restrict__ W,
                                          int arow, int brow0, int kgrp8, f32x4 acc[4]) {
  const unsigned short* ap = A + arow * HID + kgrp8;
  const unsigned short* wp = W + brow0 * HID + kgrp8;
#pragma unroll 4
  for (int ks = 0; ks < HID; ks += 32) {
    short8 a = *(const short8*)(ap + ks);
#pragma unroll
    for (int g = 0; g < 4; ++g) {
      short8 b = *(const short8*)(wp + g * (HID * HID) + ks);
      acc[g] = mfma_bf16(a, b, acc[g]);
    }
  }
}

__global__ __launch_bounds__(256) void k_gates(
    const unsigned short* __restrict__ Xin,    // [1024][512] bf16 layer input
    const unsigned short* __restrict__ Hprev,  // [1024][512] bf16
    const unsigned short* __restrict__ Wih,    // [2048][512] bf16
    const unsigned short* __restrict__ Whh,    // [2048][512] bf16
    const float* __restrict__ bias,            // [2048] fp32 (bih+bhh)
    float* __restrict__ C,                     // [1024][512] fp32 (in/out)
    unsigned short* __restrict__ Hout)         // [1024][512] bf16
{
  const int wave = threadIdx.x >> 6, lane = threadIdx.x & 63;
  const int mt = wave & 1, nt = wave >> 1;
  const int m0 = blockIdx.x * 32 + mt * 16;   // rows
  const int n0 = blockIdx.y * 32 + nt * 16;   // cells
  const int l16 = lane & 15, kgrp8 = (lane >> 4) * 8;

  f32x4 acc[4];
#pragma unroll
  for (int g = 0; g < 4; ++g) acc[g] = (f32x4)(0.0f);

  gemm_half(Xin,   Wih, m0 + l16, n0 + l16, kgrp8, acc);
  gemm_half(Hprev, Whh, m0 + l16, n0 + l16, kgrp8, acc);

  const int ccol = n0 + l16;
  const int crow = m0 + (lane >> 4) * 4;
  const float b0 = bias[ccol], b1 = bias[512 + ccol];
  const float b2 = bias[1024 + ccol], b3 = bias[1536 + ccol];
#pragma unroll
  for (int r = 0; r < 4; ++r) {
    const int m = crow + r;
    float gi = acc[0][r] + b0;
    float gf = acc[1][r] + b1;
    float gg = acc[2][r] + b2;
    float go = acc[3][r] + b3;
    float cold = C[m * HID + ccol];
    float cn = sigm(gf) * cold + sigm(gi) * tanhf(gg);
    float hn = sigm(go) * tanhf(cn);
    C[m * HID + ccol] = cn;
    Hout[m * HID + ccol] = f2bf(hn);
  }
}

// ---------------- classifier: logits + softmax ----------------
// grid 256, block 256; wave per batch row.
template <int S>
__global__ __launch_bounds__(256) void k_cls(const unsigned short* __restrict__ h1,
                                             const float* __restrict__ Wc,
                                             const float* __restrict__ bc,
                                             float* __restrict__ out, int obase) {
  const int wave = threadIdx.x >> 6, lane = threadIdx.x & 63;
  const int r = blockIdx.x * 4 + wave;
  short8 hv = *(const short8*)(h1 + r * HID + lane * 8);
  float hf[8];
#pragma unroll
  for (int j = 0; j < 8; ++j) hf[j] = bf2f((unsigned short)hv[j]);
  float logit[S];
#pragma unroll
  for (int s = 0; s < S; ++s) {
    const float* wr = Wc + s * HID + lane * 8;
    float p = 0.f;
#pragma unroll
    for (int j = 0; j < 8; ++j) p += hf[j] * wr[j];
#pragma unroll
    for (int off = 32; off; off >>= 1) p += __shfl_xor(p, off);
    logit[s] = p + bc[s];
  }
  if (lane == 0) {
    float m = logit[0];
#pragma unroll
    for (int s = 1; s < S; ++s) m = fmaxf(m, logit[s]);
    float e[S], den = 0.f;
#pragma unroll
    for (int s = 0; s < S; ++s) { e[s] = __expf(logit[s] - m); den += e[s]; }
    float inv = 1.0f / den;
#pragma unroll
    for (int s = 0; s < S; ++s) out[r * OUTW + obase + s] = e[s] * inv;
  }
}

// ---------------- anchor attention + embedding ----------------
// grid 256, block 256; wave per batch row, lane = anchor dim (64).
__global__ __launch_bounds__(256) void k_anchor(
    const unsigned short* __restrict__ h1,
    const float* __restrict__ Wprev, const float* __restrict__ bprev,
    const float* __restrict__ Wcurr, const float* __restrict__ bcurr,
    const float* __restrict__ vv,
    const float* __restrict__ Wanc, const float* __restrict__ banc,
    float* __restrict__ P,          // [12][1024][64]
    float* __restrict__ out,
    unsigned short* __restrict__ X, // next-cycle LSTM input, bf16
    int cyc) {
  __shared__ float hs[4][HID];
  __shared__ float ss[4][12];
  const int wave = threadIdx.x >> 6, lane = threadIdx.x & 63;
  const int r = blockIdx.x * 4 + wave;

  // stage h row (fp32) in LDS
  short8 hv = *(const short8*)(h1 + r * HID + lane * 8);
#pragma unroll
  for (int j = 0; j < 8; ++j) hs[wave][lane * 8 + j] = bf2f((unsigned short)hv[j]);
  __syncthreads();

  // Q[a] and Pnew[a] for a = lane
  float qa = bcurr[lane], pa = bprev[lane];
  const float* wcr = Wcurr + lane * HID;
  const float* wpr = Wprev + lane * HID;
  for (int k = 0; k < HID; k += 4) {
    float4 hk = *(const float4*)&hs[wave][k];
    float4 c4 = *(const float4*)(wcr + k);
    float4 p4 = *(const float4*)(wpr + k);
    qa += hk.x * c4.x + hk.y * c4.y + hk.z * c4.z + hk.w * c4.w;
    pa += hk.x * p4.x + hk.y * p4.y + hk.z * p4.z + hk.w * p4.w;
  }
  if (cyc + 1 < 12) P[(cyc + 1) * (BATCH * 64) + r * 64 + lane] = pa;

  // scores over previous anchors 0..cyc-1
  for (int k = 0; k < cyc; ++k) {
    float t = tanhf(P[k * (BATCH * 64) + r * 64 + lane] + qa) * vv[lane];
#pragma unroll
    for (int off = 32; off; off >>= 1) t += __shfl_xor(t, off);
    if (lane == 0) ss[wave][k] = sigm(t);
  }
  __syncthreads();

  // anchor output columns (11 wide, zero-padded)
  if (lane < 11) {
    float vo = (lane < cyc) ? ss[wave][lane] : 0.0f;
    out[r * OUTW + cyc * 29 + 18 + lane] = vo;
  }

  // next input embedding: X[r][d] = banc[d] + sum_k ss[k] * Wanc[d][k]
  const int d0 = lane * 8;
#pragma unroll
  for (int j = 0; j < 8; ++j) {
    const int d = d0 + j;
    float x = banc[d];
    for (int k = 0; k < cyc; ++k) x += ss[wave][k] * Wanc[d * 11 + k];
    X[r * HID + d] = f2bf(x);
  }
}

// ---------------- launcher ----------------

extern "C" void kernel_launch(void* const* d_in, const int* in_sizes, int n_in,
                              void* d_out, int out_size, void* d_ws, size_t ws_size,
                              hipStream_t stream) {
  const float* x0    = (const float*)d_in[0];
  const float* lWih  = (const float*)d_in[1];
  const float* lWhh  = (const float*)d_in[2];
  const float* lbih  = (const float*)d_in[3];
  const float* lbhh  = (const float*)d_in[4];
  const float* Wc0   = (const float*)d_in[5];
  const float* bc0   = (const float*)d_in[6];
  const float* Wc1   = (const float*)d_in[7];
  const float* bc1   = (const float*)d_in[8];
  const float* Wc2   = (const float*)d_in[9];
  const float* bc2   = (const float*)d_in[10];
  const float* Wprev = (const float*)d_in[11];
  const float* bprev = (const float*)d_in[12];
  const float* Wcurr = (const float*)d_in[13];
  const float* bcurr = (const float*)d_in[14];
  const float* Wanc  = (const float*)d_in[15];
  const float* banc  = (const float*)d_in[16];
  const float* v     = (const float*)d_in[17];
  float* out = (float*)d_out;

  const size_t NW  = 2 * 2048 * 512;      // lstm weight elems per matrix set
  const size_t NBH = (size_t)BATCH * HID; // 524288

  char* ws = (char*)d_ws;
  size_t off = 0;
  auto alloc = [&](size_t bytes) { char* p = ws + off; off += (bytes + 255) & ~(size_t)255; return p; };
  unsigned short* Wih_b = (unsigned short*)alloc(NW * 2);
  unsigned short* Whh_b = (unsigned short*)alloc(NW * 2);
  float*          biasS = (float*)alloc(4096 * 4);
  unsigned short* Xb    = (unsigned short*)alloc(NBH * 2);
  unsigned short* Hb0   = (unsigned short*)alloc(2 * NBH * 2);  // [2][B][H]
  unsigned short* Hb1   = (unsigned short*)alloc(2 * NBH * 2);
  float*          C0    = (float*)alloc(NBH * 4);
  float*          C1    = (float*)alloc(NBH * 4);
  float*          P     = (float*)alloc((size_t)12 * BATCH * 64 * 4);

  // setup: convert weights/x0 to bf16, sum biases, zero h/c, init P[0]
  k_convert<<<dim3((NW / 4 + 255) / 256), dim3(256), 0, stream>>>(lWih, Wih_b, (int)NW);
  k_convert<<<dim3((NW / 4 + 255) / 256), dim3(256), 0, stream>>>(lWhh, Whh_b, (int)NW);
  k_convert<<<dim3((NBH / 4 + 255) / 256), dim3(256), 0, stream>>>(x0, Xb, (int)NBH);
  k_bias<<<dim3(16), dim3(256), 0, stream>>>(lbih, lbhh, biasS);
  {
    // zero Hb0, Hb1, C0, C1: contiguous span in ws (all sizes are 256B multiples)
    size_t zb = 2 * NBH * 2 + 2 * NBH * 2 + NBH * 4 + NBH * 4;  // 12 MB
    int n16 = (int)(zb / 16);
    k_zero<<<dim3((n16 + 255) / 256), dim3(256), 0, stream>>>((uint4*)Hb0, n16);
  }
  k_p0<<<dim3(256), dim3(256), 0, stream>>>(P, bprev);

  for (int t = 0; t < 48; ++t) {
    const int rd = t & 1, wr = (t + 1) & 1;
    unsigned short* h0r = Hb0 + rd * NBH;
    unsigned short* h0w = Hb0 + wr * NBH;
    unsigned short* h1r = Hb1 + rd * NBH;
    unsigned short* h1w = Hb1 + wr * NBH;

    k_gates<<<dim3(32, 16), dim3(256), 0, stream>>>(Xb, h0r, Wih_b, Whh_b, biasS, C0, h0w);
    k_gates<<<dim3(32, 16), dim3(256), 0, stream>>>(h0w, h1r, Wih_b + 2048 * 512,
                                                    Whh_b + 2048 * 512, biasS + 2048, C1, h1w);
    const int st = t & 3, cyc = t >> 2, base = cyc * 29;
    if (st == 0)      k_cls<8><<<dim3(256), dim3(256), 0, stream>>>(h1w, Wc0, bc0, out, base);
    else if (st == 1) k_cls<6><<<dim3(256), dim3(256), 0, stream>>>(h1w, Wc1, bc1, out, base + 8);
    else if (st == 2) k_cls<4><<<dim3(256), dim3(256), 0, stream>>>(h1w, Wc2, bc2, out, base + 14);
    else              k_anchor<<<dim3(256), dim3(256), 0, stream>>>(h1w, Wprev, bprev, Wcurr, bcurr,
                                                                    v, Wanc, banc, P, out, Xb, cyc);
  }
  (void)in_sizes; (void)n_in; (void)out_size; (void)ws_size;
}

// Round 2
// 1698.024 us; speedup vs baseline: 2.5406x; 2.5406x over previous
//
#include <hip/hip_runtime.h>
#include <hip/hip_bf16.h>

#define BATCH 1024
#define HID   512
#define OUTW  348   // 12 * (8+6+4+11)
#define BK    64

using short8 = __attribute__((ext_vector_type(8))) short;
using bf16x8 = __attribute__((ext_vector_type(8))) __bf16;
using f32x4  = __attribute__((ext_vector_type(4))) float;

__device__ __forceinline__ float bf2f(unsigned short u) {
  union { unsigned int i; float f; } x; x.i = ((unsigned int)u) << 16; return x.f;
}
__device__ __forceinline__ unsigned short f2bf(float f) {
  __hip_bfloat16 b = __float2bfloat16(f);
  return __builtin_bit_cast(unsigned short, b);
}
__device__ __forceinline__ float sigm(float x) { return 1.0f / (1.0f + __expf(-x)); }

__device__ __forceinline__ f32x4 mfma_bf16(short8 a, short8 b, f32x4 c) {
  return __builtin_amdgcn_mfma_f32_16x16x32_bf16(
      __builtin_bit_cast(bf16x8, a), __builtin_bit_cast(bf16x8, b), c, 0, 0, 0);
}

typedef const __attribute__((address_space(1))) unsigned int* gas_p;
typedef __attribute__((address_space(3))) unsigned int* las_p;
__device__ __forceinline__ void gload16(const void* g, void* l) {
  __builtin_amdgcn_global_load_lds((gas_p)g, (las_p)l, 16, 0, 0);
}

// ---------------- setup kernels ----------------

__global__ void k_convert(const float* __restrict__ src, unsigned short* __restrict__ dst, int n) {
  int i = (blockIdx.x * blockDim.x + threadIdx.x) * 4;
  if (i + 3 < n) {
    float4 v = *(const float4*)(src + i);
    dst[i + 0] = f2bf(v.x); dst[i + 1] = f2bf(v.y);
    dst[i + 2] = f2bf(v.z); dst[i + 3] = f2bf(v.w);
  } else {
    for (int j = 0; j < 4 && i + j < n; ++j) dst[i + j] = f2bf(src[i + j]);
  }
}

// Wqp[128][512] bf16: rows 0..63 = Wcurr, 64..127 = Wprev
__global__ void k_wqp(const float* __restrict__ Wcurr, const float* __restrict__ Wprev,
                      unsigned short* __restrict__ dst) {
  int i = blockIdx.x * blockDim.x + threadIdx.x;  // < 128*512
  int row = i >> 9, col = i & 511;
  float v = (row < 64) ? Wcurr[row * 512 + col] : Wprev[(row - 64) * 512 + col];
  dst[i] = f2bf(v);
}

__global__ void k_bias(const float* __restrict__ bih, const float* __restrict__ bhh,
                       float* __restrict__ bsum) {
  int i = blockIdx.x * blockDim.x + threadIdx.x;
  if (i < 4096) bsum[i] = bih[i] + bhh[i];
}

__global__ void k_zero(uint4* __restrict__ p, int n16) {
  int i = blockIdx.x * blockDim.x + threadIdx.x;
  if (i < n16) p[i] = make_uint4(0u, 0u, 0u, 0u);
}

// P[0][r][a] = bprev[a]
__global__ void k_p0(float* __restrict__ P, const float* __restrict__ bprev) {
  int i = blockIdx.x * blockDim.x + threadIdx.x;  // < 1024*64
  P[i] = bprev[i & 63];
}

// ---------------- LSTM gates + cell update (LDS-staged, double-buffered) ----------------
// Tile: BM=64 batch rows x 16 cells (64 gate rows), BK=64, K=1024 (X||H).
// Grid (16,32)=512 blocks, 256 thr (4 waves). Wave w: rows w*16..w*16+15, all 16 cells x 4 gates.
// LDS XOR-swizzle (granule ^= row&7), applied on the GLOBAL SOURCE side for global_load_lds.
__global__ __launch_bounds__(256) void k_gates(
    const unsigned short* __restrict__ Xin,    // [1024][512] bf16
    const unsigned short* __restrict__ Hprev,  // [1024][512] bf16
    const unsigned short* __restrict__ Wih,    // [2048][512] bf16
    const unsigned short* __restrict__ Whh,    // [2048][512] bf16
    const float* __restrict__ bias,            // [2048] fp32
    float* __restrict__ C,                     // [1024][512] fp32 (in/out)
    unsigned short* __restrict__ Hout)         // [1024][512] bf16
{
  __shared__ unsigned short Ab[2][4096];  // [64 rows][64 bf16]
  __shared__ unsigned short Bb[2][4096];  // [4 gates*16 cells][64 bf16]
  const int w = threadIdx.x >> 6, lane = threadIdx.x & 63;
  const int m0 = blockIdx.x * 64;
  const int n0 = blockIdx.y * 16;
  const int l16 = lane & 15, kg = lane >> 4;

  auto stage = [&](int kt, int buf) {
    const unsigned short* Asrc = (kt < 8) ? Xin : Hprev;
    const unsigned short* Wsrc = (kt < 8) ? Wih : Whh;
    const int k0 = (kt & 7) * BK;
#pragma unroll
    for (int j = 0; j < 2; ++j) {
      int s = w * 128 + j * 64 + lane;
      int row = s >> 3;
      int ke = ((s & 7) ^ (row & 7)) << 3;  // swizzled source element offset
      gload16(Asrc + (size_t)(m0 + row) * HID + k0 + ke, &Ab[buf][(w * 128 + j * 64) * 8]);
    }
#pragma unroll
    for (int j = 0; j < 2; ++j) {
      int s = w * 128 + j * 64 + lane;
      int fr = s >> 3;                       // 0..63 = g*16+c
      int g = fr >> 4, c = fr & 15;
      int ke = ((s & 7) ^ (fr & 7)) << 3;
      gload16(Wsrc + (size_t)(g * 512 + n0 + c) * HID + k0 + ke, &Bb[buf][(w * 128 + j * 64) * 8]);
    }
  };

  f32x4 acc[4];
#pragma unroll
  for (int g = 0; g < 4; ++g) acc[g] = (f32x4)(0.0f);

  stage(0, 0);
  for (int kt = 0; kt < 16; ++kt) {
    __syncthreads();
    if (kt < 15) stage(kt + 1, (kt + 1) & 1);
    const int buf = kt & 1;
#pragma unroll
    for (int ko = 0; ko < 2; ++ko) {
      const int acb = ko * 64 + kg * 16;       // logical col byte within 128B row
      const int ar = w * 16 + l16;
      short8 a = *(const short8*)&Ab[buf][ar * 64 + ((acb ^ ((ar & 7) << 4)) >> 1)];
#pragma unroll
      for (int g = 0; g < 4; ++g) {
        const int br = g * 16 + l16;
        short8 b = *(const short8*)&Bb[buf][br * 64 + ((acb ^ ((br & 7) << 4)) >> 1)];
        acc[g] = mfma_bf16(a, b, acc[g]);
      }
    }
  }

  const int ccol = n0 + l16;
  const int crow = m0 + w * 16 + kg * 4;
  const float b0 = bias[ccol], b1 = bias[512 + ccol];
  const float b2 = bias[1024 + ccol], b3 = bias[1536 + ccol];
#pragma unroll
  for (int r = 0; r < 4; ++r) {
    const int m = crow + r;
    float gi = acc[0][r] + b0;
    float gf = acc[1][r] + b1;
    float gg = acc[2][r] + b2;
    float go = acc[3][r] + b3;
    float cold = C[m * HID + ccol];
    float cn = sigm(gf) * cold + sigm(gi) * tanhf(gg);
    float hn = sigm(go) * tanhf(cn);
    C[m * HID + ccol] = cn;
    Hout[m * HID + ccol] = f2bf(hn);
  }
}

// ---------------- classifier: logits + softmax ----------------
template <int S>
__global__ __launch_bounds__(256) void k_cls(const unsigned short* __restrict__ h1,
                                             const float* __restrict__ Wc,
                                             const float* __restrict__ bc,
                                             float* __restrict__ out, int obase) {
  const int wave = threadIdx.x >> 6, lane = threadIdx.x & 63;
  const int r = blockIdx.x * 4 + wave;
  short8 hv = *(const short8*)(h1 + r * HID + lane * 8);
  float hf[8];
#pragma unroll
  for (int j = 0; j < 8; ++j) hf[j] = bf2f((unsigned short)hv[j]);
  float logit[S];
#pragma unroll
  for (int s = 0; s < S; ++s) {
    const float* wr = Wc + s * HID + lane * 8;
    float p = 0.f;
#pragma unroll
    for (int j = 0; j < 8; ++j) p += hf[j] * wr[j];
#pragma unroll
    for (int off = 32; off; off >>= 1) p += __shfl_xor(p, off);
    logit[s] = p + bc[s];
  }
  if (lane == 0) {
    float m = logit[0];
#pragma unroll
    for (int s = 1; s < S; ++s) m = fmaxf(m, logit[s]);
    float e[S], den = 0.f;
#pragma unroll
    for (int s = 0; s < S; ++s) { e[s] = __expf(logit[s] - m); den += e[s]; }
    float inv = 1.0f / den;
#pragma unroll
    for (int s = 0; s < S; ++s) out[r * OUTW + obase + s] = e[s] * inv;
  }
}

// ---------------- anchor projections: [Q || Pnew] = h1 @ Wqp^T (MFMA, staged) ----------------
// Grid (16,8), 256 thr. BM=64, BN=16, K=512.
__global__ __launch_bounds__(256) void k_qp(
    const unsigned short* __restrict__ h1,
    const unsigned short* __restrict__ Wqp,   // [128][512] bf16
    const float* __restrict__ bcurr, const float* __restrict__ bprev,
    float* __restrict__ Q,                    // [1024][64]
    float* __restrict__ P,                    // [12][1024][64]
    int cyc) {
  __shared__ unsigned short Ab[2][4096];
  __shared__ unsigned short Bb[2][1024];
  const int w = threadIdx.x >> 6, lane = threadIdx.x & 63;
  const int m0 = blockIdx.x * 64, n0 = blockIdx.y * 16;
  const int l16 = lane & 15, kg = lane >> 4;

  auto stage = [&](int kt, int buf) {
    const int k0 = kt * BK;
#pragma unroll
    for (int j = 0; j < 2; ++j) {
      int s = w * 128 + j * 64 + lane;
      int row = s >> 3;
      int ke = ((s & 7) ^ (row & 7)) << 3;
      gload16(h1 + (size_t)(m0 + row) * HID + k0 + ke, &Ab[buf][(w * 128 + j * 64) * 8]);
    }
    if (w < 2) {
      int s = w * 64 + lane;
      int row = s >> 3;
      int ke = ((s & 7) ^ (row & 7)) << 3;
      gload16(Wqp + (size_t)(n0 + row) * HID + k0 + ke, &Bb[buf][(w * 64) * 8]);
    }
  };

  f32x4 acc = (f32x4)(0.0f);
  stage(0, 0);
  for (int kt = 0; kt < 8; ++kt) {
    __syncthreads();
    if (kt < 7) stage(kt + 1, (kt + 1) & 1);
    const int buf = kt & 1;
#pragma unroll
    for (int ko = 0; ko < 2; ++ko) {
      const int acb = ko * 64 + kg * 16;
      const int ar = w * 16 + l16;
      short8 a = *(const short8*)&Ab[buf][ar * 64 + ((acb ^ ((ar & 7) << 4)) >> 1)];
      const int br = l16;
      short8 b = *(const short8*)&Bb[buf][br * 64 + ((acb ^ ((br & 7) << 4)) >> 1)];
      acc = mfma_bf16(a, b, acc);
    }
  }

  const int col = n0 + l16;
  const int r0 = m0 + w * 16 + kg * 4;
#pragma unroll
  for (int r = 0; r < 4; ++r) {
    const int m = r0 + r;
    float val = acc[r] + (col < 64 ? bcurr[col] : bprev[col - 64]);
    if (col < 64) Q[m * 64 + col] = val;
    else if (cyc + 1 < 12) P[(cyc + 1) * (BATCH * 64) + m * 64 + (col - 64)] = val;
  }
}

// ---------------- anchor scores + embedding ----------------
// grid 256, block 256; wave per batch row, lane = anchor dim. CYC compile-time.
template <int CYC>
__global__ __launch_bounds__(256) void k_scores(
    const float* __restrict__ Q, const float* __restrict__ P,
    const float* __restrict__ vv, const float* __restrict__ Wanc,
    const float* __restrict__ banc, float* __restrict__ out,
    unsigned short* __restrict__ X) {
  const int w = threadIdx.x >> 6, lane = threadIdx.x & 63;
  const int r = blockIdx.x * 4 + w;
  const float q = Q[r * 64 + lane];
  const float vl = vv[lane];
  float sk[CYC > 0 ? CYC : 1];
#pragma unroll
  for (int k = 0; k < CYC; ++k) {
    float t = tanhf(P[k * (BATCH * 64) + r * 64 + lane] + q) * vl;
#pragma unroll
    for (int off = 32; off; off >>= 1) t += __shfl_xor(t, off);
    sk[k] = sigm(t);
  }
  float ov = 0.0f;
#pragma unroll
  for (int k = 0; k < 11; ++k)
    if (lane == k) ov = (k < CYC) ? sk[k] : 0.0f;
  if (lane < 11) out[r * OUTW + CYC * 29 + 18 + lane] = ov;

  const int d0 = lane * 8;
#pragma unroll
  for (int j = 0; j < 8; ++j) {
    const int d = d0 + j;
    float x = banc[d];
#pragma unroll
    for (int k = 0; k < CYC; ++k) x += sk[k] * Wanc[d * 11 + k];
    X[r * HID + d] = f2bf(x);
  }
}

// ---------------- launcher ----------------

extern "C" void kernel_launch(void* const* d_in, const int* in_sizes, int n_in,
                              void* d_out, int out_size, void* d_ws, size_t ws_size,
                              hipStream_t stream) {
  const float* x0    = (const float*)d_in[0];
  const float* lWih  = (const float*)d_in[1];
  const float* lWhh  = (const float*)d_in[2];
  const float* lbih  = (const float*)d_in[3];
  const float* lbhh  = (const float*)d_in[4];
  const float* Wc0   = (const float*)d_in[5];
  const float* bc0   = (const float*)d_in[6];
  const float* Wc1   = (const float*)d_in[7];
  const float* bc1   = (const float*)d_in[8];
  const float* Wc2   = (const float*)d_in[9];
  const float* bc2   = (const float*)d_in[10];
  const float* Wprev = (const float*)d_in[11];
  const float* bprev = (const float*)d_in[12];
  const float* Wcurr = (const float*)d_in[13];
  const float* bcurr = (const float*)d_in[14];
  const float* Wanc  = (const float*)d_in[15];
  const float* banc  = (const float*)d_in[16];
  const float* v     = (const float*)d_in[17];
  float* out = (float*)d_out;

  const size_t NW  = 2 * 2048 * 512;
  const size_t NBH = (size_t)BATCH * HID;

  char* ws = (char*)d_ws;
  size_t off = 0;
  auto alloc = [&](size_t bytes) { char* p = ws + off; off += (bytes + 255) & ~(size_t)255; return p; };
  unsigned short* Wih_b = (unsigned short*)alloc(NW * 2);
  unsigned short* Whh_b = (unsigned short*)alloc(NW * 2);
  unsigned short* Wqp_b = (unsigned short*)alloc(128 * 512 * 2);
  float*          biasS = (float*)alloc(4096 * 4);
  unsigned short* Xb    = (unsigned short*)alloc(NBH * 2);
  unsigned short* Hb0   = (unsigned short*)alloc(2 * NBH * 2);
  unsigned short* Hb1   = (unsigned short*)alloc(2 * NBH * 2);
  float*          C0    = (float*)alloc(NBH * 4);
  float*          C1    = (float*)alloc(NBH * 4);
  float*          P     = (float*)alloc((size_t)12 * BATCH * 64 * 4);
  float*          Qb    = (float*)alloc((size_t)BATCH * 64 * 4);

  k_convert<<<dim3((NW / 4 + 255) / 256), dim3(256), 0, stream>>>(lWih, Wih_b, (int)NW);
  k_convert<<<dim3((NW / 4 + 255) / 256), dim3(256), 0, stream>>>(lWhh, Whh_b, (int)NW);
  k_convert<<<dim3((NBH / 4 + 255) / 256), dim3(256), 0, stream>>>(x0, Xb, (int)NBH);
  k_wqp<<<dim3(256), dim3(256), 0, stream>>>(Wcurr, Wprev, Wqp_b);
  k_bias<<<dim3(16), dim3(256), 0, stream>>>(lbih, lbhh, biasS);
  {
    size_t zb = 2 * NBH * 2 + 2 * NBH * 2 + NBH * 4 + NBH * 4;  // Hb0,Hb1,C0,C1 contiguous
    int n16 = (int)(zb / 16);
    k_zero<<<dim3((n16 + 255) / 256), dim3(256), 0, stream>>>((uint4*)Hb0, n16);
  }
  k_p0<<<dim3(256), dim3(256), 0, stream>>>(P, bprev);

  for (int t = 0; t < 48; ++t) {
    const int rd = t & 1, wr = (t + 1) & 1;
    unsigned short* h0r = Hb0 + rd * NBH;
    unsigned short* h0w = Hb0 + wr * NBH;
    unsigned short* h1r = Hb1 + rd * NBH;
    unsigned short* h1w = Hb1 + wr * NBH;

    k_gates<<<dim3(16, 32), dim3(256), 0, stream>>>(Xb, h0r, Wih_b, Whh_b, biasS, C0, h0w);
    k_gates<<<dim3(16, 32), dim3(256), 0, stream>>>(h0w, h1r, Wih_b + 2048 * 512,
                                                    Whh_b + 2048 * 512, biasS + 2048, C1, h1w);
    const int st = t & 3, cyc = t >> 2, base = cyc * 29;
    if (st == 0)      k_cls<8><<<dim3(256), dim3(256), 0, stream>>>(h1w, Wc0, bc0, out, base);
    else if (st == 1) k_cls<6><<<dim3(256), dim3(256), 0, stream>>>(h1w, Wc1, bc1, out, base + 8);
    else if (st == 2) k_cls<4><<<dim3(256), dim3(256), 0, stream>>>(h1w, Wc2, bc2, out, base + 14);
    else {
      k_qp<<<dim3(16, 8), dim3(256), 0, stream>>>(h1w, Wqp_b, bcurr, bprev, Qb, P, cyc);
      switch (cyc) {
        case 0:  k_scores<0><<<dim3(256), dim3(256), 0, stream>>>(Qb, P, v, Wanc, banc, out, Xb); break;
        case 1:  k_scores<1><<<dim3(256), dim3(256), 0, stream>>>(Qb, P, v, Wanc, banc, out, Xb); break;
        case 2:  k_scores<2><<<dim3(256), dim3(256), 0, stream>>>(Qb, P, v, Wanc, banc, out, Xb); break;
        case 3:  k_scores<3><<<dim3(256), dim3(256), 0, stream>>>(Qb, P, v, Wanc, banc, out, Xb); break;
        case 4:  k_scores<4><<<dim3(256), dim3(256), 0, stream>>>(Qb, P, v, Wanc, banc, out, Xb); break;
        case 5:  k_scores<5><<<dim3(256), dim3(256), 0, stream>>>(Qb, P, v, Wanc, banc, out, Xb); break;
        case 6:  k_scores<6><<<dim3(256), dim3(256), 0, stream>>>(Qb, P, v, Wanc, banc, out, Xb); break;
        case 7:  k_scores<7><<<dim3(256), dim3(256), 0, stream>>>(Qb, P, v, Wanc, banc, out, Xb); break;
        case 8:  k_scores<8><<<dim3(256), dim3(256), 0, stream>>>(Qb, P, v, Wanc, banc, out, Xb); break;
        case 9:  k_scores<9><<<dim3(256), dim3(256), 0, stream>>>(Qb, P, v, Wanc, banc, out, Xb); break;
        case 10: k_scores<10><<<dim3(256), dim3(256), 0, stream>>>(Qb, P, v, Wanc, banc, out, Xb); break;
        default: k_scores<11><<<dim3(256), dim3(256), 0, stream>>>(Qb, P, v, Wanc, banc, out, Xb); break;
      }
    }
  }
  (void)in_sizes; (void)n_in; (void)out_size; (void)ws_size;
}